// Round 3
// baseline (597.602 us; speedup 1.0000x reference)
//
#include <hip/hip_runtime.h>
#include <math.h>

#define B_N    64
#define H_N    512
#define V_N    32000
#define S_N    512
#define VEXT   32050
#define INF_F  1000000000000.0f

typedef __attribute__((ext_vector_type(4))) float floatx4;
typedef __attribute__((ext_vector_type(8))) __bf16 bf16x8;

// ---- output layout (floats) ----
#define OFF_OUT0 0
#define OFF_CTX  (B_N * VEXT)                 // 2051200
#define OFF_H1   (OFF_CTX + B_N * H_N)        // 2083968
#define OFF_C1   (OFF_H1 + B_N * H_N)        // 2116736
#define OFF_ATTN (OFF_C1 + B_N * H_N)        // 2149504

// ---- workspace layout (32-bit words) ----
#define WS_FLAG   0
#define WS_X      16
#define WS_GATES  (WS_X + B_N * H_N)                  // 32784
#define WS_Q      (WS_GATES + B_N * 4 * H_N)          // 163856
#define WS_KB     (WS_Q + B_N * H_N)                  // 196624
#define WS_EN     (WS_KB + B_N)                       // 196688
#define WS_COMB   (WS_EN + B_N * S_N)                 // 229456
#define WS_SEQE   (WS_COMB + B_N * H_N)               // 262224 (unused now; kept for layout)
#define WS_WSKBF  (WS_SEQE + B_N * S_N)               // 294992 (512*512 ushort, swizzled, HI part)
#define WS_LOGITS (WS_WSKBF + (H_N * H_N) / 2)        // 426064
// W_lo (512*512 ushort = 131072 words) OVERLAYS the head of WS_LOGITS.
// Legal because kSeqGemm (reader) completes before kLogits (writer) on the stream.
#define WS_COPY   (WS_LOGITS + B_N * V_N)             // 2474064
#define WS_RMAX   (WS_COPY + B_N * VEXT)              // 4525264 (64 uints)
#define WS_RSUM   (WS_RMAX + B_N)                     // +64 floats

__device__ __forceinline__ float sigm(float x) { return 1.0f / (1.0f + expf(-x)); }

__device__ __forceinline__ unsigned short f2bf(float f) {
    unsigned u = __float_as_uint(f);
    u += 0x7fffu + ((u >> 16) & 1u);   // round-to-nearest-even
    return (unsigned short)(u >> 16);
}
__device__ __forceinline__ float bf2f(unsigned short h) {
    return __uint_as_float(((unsigned)h) << 16);
}

// order-preserving float<->uint encode for atomicMax-based scatter-max
__device__ __forceinline__ unsigned enc_f(float f) {
    unsigned u = __float_as_uint(f);
    return (u & 0x80000000u) ? ~u : (u | 0x80000000u);
}
__device__ __forceinline__ float dec_f(unsigned e) {
    unsigned u = (e & 0x80000000u) ? (e & 0x7fffffffu) : ~e;
    return __uint_as_float(u);
}

// ---------- detect bool-mask storage width (1 byte vs 4 byte) ----------
__global__ void kDetect(const unsigned int* __restrict__ m, int* __restrict__ flag) {
    __shared__ int any;
    if (threadIdx.x == 0) any = 0;
    __syncthreads();
    int loc = 0;
    for (int i = threadIdx.x; i < 8192; i += 256) loc |= (m[i] > 1u) ? 1 : 0;
    if (loc) any = 1;
    __syncthreads();
    if (threadIdx.x == 0) *flag = any;   // 1 => byte storage, 0 => int32 storage
}

// ---------- W_seqkey f32 -> bf16 hi/lo split, pre-swizzled to MFMA B-fragment order ----
// layout: swz[((t*16 + kc)*64 + lane)*8 + j] = W[(t*16 + (lane&15))*512 + kc*32 + (lane>>4)*8 + j]
// hi = bf16(w); lo = bf16(w - hi). K = Ah*Bh + Al*Bh + Ah*Bl recovers ~f32 precision.
__global__ void kConvertW(const float* __restrict__ W, unsigned short* __restrict__ swzh,
                          unsigned short* __restrict__ swzl) {
    const int g = blockIdx.x * 256 + threadIdx.x;      // 32768 threads, 8 elems each
    const int t = g >> 10, kc = (g >> 6) & 15, lane = g & 63;
    const int r = t * 16 + (lane & 15);
    const int k = kc * 32 + (lane >> 4) * 8;
    const float* src = W + (size_t)r * 512 + k;
    ushort4 h0, h1, l0, l1;
    {
        const float4 v0 = *(const float4*)(src);
        const float4 v1 = *(const float4*)(src + 4);
        h0.x = f2bf(v0.x); l0.x = f2bf(v0.x - bf2f(h0.x));
        h0.y = f2bf(v0.y); l0.y = f2bf(v0.y - bf2f(h0.y));
        h0.z = f2bf(v0.z); l0.z = f2bf(v0.z - bf2f(h0.z));
        h0.w = f2bf(v0.w); l0.w = f2bf(v0.w - bf2f(h0.w));
        h1.x = f2bf(v1.x); l1.x = f2bf(v1.x - bf2f(h1.x));
        h1.y = f2bf(v1.y); l1.y = f2bf(v1.y - bf2f(h1.y));
        h1.z = f2bf(v1.z); l1.z = f2bf(v1.z - bf2f(h1.z));
        h1.w = f2bf(v1.w); l1.w = f2bf(v1.w - bf2f(h1.w));
    }
    *(ushort4*)(swzh + (size_t)g * 8) = h0;
    *(ushort4*)(swzh + (size_t)g * 8 + 4) = h1;
    *(ushort4*)(swzl + (size_t)g * 8) = l0;
    *(ushort4*)(swzl + (size_t)g * 8 + 4) = l1;
}

// ---------- init copy buffer to enc(-INF); block 0 also inits row max/sum ----------
__global__ void kFillCopy(unsigned int* __restrict__ copyenc,
                          unsigned int* __restrict__ rmax, float* __restrict__ rsum) {
    const unsigned NE = enc_f(-INF_F);
    if (blockIdx.x == 0 && threadIdx.x < B_N) {
        rmax[threadIdx.x] = 0u;
        rsum[threadIdx.x] = 0.0f;
    }
    int i0 = (blockIdx.x * 256 + threadIdx.x) * 4;
#pragma unroll
    for (int k = 0; k < 4; k++) {
        int i = i0 + k;
        if (i < B_N * VEXT) copyenc[i] = NE;
    }
}

// ---------- x = [embed[id] | prev_context] @ W_reduce.T + b_reduce ----------
__global__ __launch_bounds__(256) void kEmbedReduce(
        const int* __restrict__ ids, const float* __restrict__ embed,
        const float* __restrict__ pctx, const float* __restrict__ Wred,
        const float* __restrict__ bred, float* __restrict__ x) {
    __shared__ float xc[1024];
    const int tid = threadIdx.x;
    const int b = blockIdx.x >> 1, half = blockIdx.x & 1;
    const float* er = embed + (size_t)ids[b] * 512;
    xc[tid] = er[tid];               xc[tid + 256] = er[tid + 256];
    xc[512 + tid] = pctx[b * 512 + tid]; xc[512 + tid + 256] = pctx[b * 512 + tid + 256];
    __syncthreads();
    const int j = half * 256 + tid;
    const float4* w4 = (const float4*)(Wred + (size_t)j * 1024);
    const float4* x4 = (const float4*)xc;
    float acc = bred[j];
    for (int k = 0; k < 256; k++) {
        float4 w = w4[k], xv = x4[k];
        acc += w.x * xv.x + w.y * xv.y + w.z * xv.z + w.w * xv.w;
    }
    x[b * 512 + j] = acc;
}

// ---------- gates = x @ W_ih.T + h0 @ W_hh.T + b_ih + b_hh ----------
__global__ __launch_bounds__(256) void kGates(
        const float* __restrict__ x, const float* __restrict__ h0,
        const float* __restrict__ Wih, const float* __restrict__ Whh,
        const float* __restrict__ bih, const float* __restrict__ bhh,
        float* __restrict__ gates) {
    __shared__ float xl[512], hl[512];
    const int tid = threadIdx.x;
    const int b = blockIdx.x >> 3, part = blockIdx.x & 7;
    xl[tid] = x[b * 512 + tid];  xl[tid + 256] = x[b * 512 + tid + 256];
    hl[tid] = h0[b * 512 + tid]; hl[tid + 256] = h0[b * 512 + tid + 256];
    __syncthreads();
    const int j = part * 256 + tid;
    const float4* wi4 = (const float4*)(Wih + (size_t)j * 512);
    const float4* wh4 = (const float4*)(Whh + (size_t)j * 512);
    const float4* x4 = (const float4*)xl;
    const float4* h4 = (const float4*)hl;
    float acc = bih[j] + bhh[j];
    for (int k = 0; k < 128; k++) {
        float4 w = wi4[k], xv = x4[k];
        acc += w.x * xv.x + w.y * xv.y + w.z * xv.z + w.w * xv.w;
    }
    for (int k = 0; k < 128; k++) {
        float4 w = wh4[k], hv = h4[k];
        acc += w.x * hv.x + w.y * hv.y + w.z * hv.z + w.w * hv.w;
    }
    gates[(size_t)b * 2048 + j] = acc;
}

// ---------- LSTM elementwise (PyTorch i,f,g,o order) ----------
__global__ __launch_bounds__(256) void kLstm(
        const float* __restrict__ gates, const float* __restrict__ c0,
        float* __restrict__ h1o, float* __restrict__ c1o) {
    const int idx = blockIdx.x * 256 + threadIdx.x;  // < 32768
    const int b = idx >> 9, j = idx & 511;
    const float gi = gates[(size_t)b * 2048 + j];
    const float gf = gates[(size_t)b * 2048 + 512 + j];
    const float gg = gates[(size_t)b * 2048 + 1024 + j];
    const float go = gates[(size_t)b * 2048 + 1536 + j];
    const float cp = c0[idx];
    const float c1 = sigm(gf) * cp + sigm(gi) * tanhf(gg);
    const float h1 = sigm(go) * tanhf(c1);
    h1o[idx] = h1;
    c1o[idx] = c1;
}

// ---------- q[b,k] = sum_h h1[b,h]*W_key[h,k]; kb[b] = b_key . h1[b] ----------
__global__ __launch_bounds__(256) void kQ(
        const float* __restrict__ h1, const float* __restrict__ Wkey,
        const float* __restrict__ bkey, float* __restrict__ q, float* __restrict__ kb) {
    __shared__ float hl[512];
    __shared__ float rd[256];
    const int tid = threadIdx.x;
    const int b = blockIdx.x >> 1, half = blockIdx.x & 1;
    hl[tid] = h1[b * 512 + tid]; hl[tid + 256] = h1[b * 512 + tid + 256];
    __syncthreads();
    const int k = half * 256 + tid;
    float acc = 0.f;
#pragma unroll 4
    for (int h = 0; h < 512; h++) acc += hl[h] * Wkey[(size_t)h * 512 + k];
    q[b * 512 + k] = acc;
    if (half == 0) {   // block-uniform branch
        float p = bkey[tid] * hl[tid] + bkey[tid + 256] * hl[tid + 256];
        rd[tid] = p; __syncthreads();
        for (int st = 128; st > 0; st >>= 1) {
            if (tid < st) rd[tid] += rd[tid + st];
            __syncthreads();
        }
        if (tid == 0) kb[b] = rd[0];
    }
}

// ---------- energies[b,s] = enc[b,s,:].q[b] + kb[b]; mask rows summing to 0 ----------
__global__ __launch_bounds__(256) void kEnergies(
        const float* __restrict__ enc, const float* __restrict__ q,
        const float* __restrict__ kb, float* __restrict__ energ) {
    __shared__ float ql[512];
    __shared__ float pe[256], ps[256];
    const int tid = threadIdx.x;
    const int b = blockIdx.x >> 2;
    const int sc = (blockIdx.x & 3) * 128;
    ql[tid] = q[b * 512 + tid]; ql[tid + 256] = q[b * 512 + tid + 256];
    __syncthreads();
    const int r = tid & 127, hi = tid >> 7;
    const float4* row4 = (const float4*)(enc + (size_t)(b * 512 + sc + r) * 512 + hi * 256);
    const float4* q4 = (const float4*)(ql + hi * 256);
    float e = 0.f, ssum = 0.f;
#pragma unroll 4
    for (int k = 0; k < 64; k++) {
        float4 ev = row4[k], qv = q4[k];
        e += ev.x * qv.x + ev.y * qv.y + ev.z * qv.z + ev.w * qv.w;
        ssum += ev.x + ev.y + ev.z + ev.w;
    }
    pe[tid] = e; ps[tid] = ssum;
    __syncthreads();
    if (tid < 128) {
        float ee = pe[tid] + pe[tid + 128] + kb[b];
        float sm = ps[tid] + ps[tid + 128];
        if (sm == 0.0f) ee = 1e-12f;        // enc_mask semantics
        energ[b * 512 + sc + tid] = ee;
    }
}

// ---------- softmax over S per b ----------
__global__ __launch_bounds__(256) void kSoftmax(
        const float* __restrict__ energ, float* __restrict__ attn) {
    __shared__ float el[512];
    __shared__ float rd[256];
    const int tid = threadIdx.x, b = blockIdx.x;
    el[tid] = energ[b * 512 + tid]; el[tid + 256] = energ[b * 512 + tid + 256];
    __syncthreads();
    rd[tid] = fmaxf(el[tid], el[tid + 256]); __syncthreads();
    for (int st = 128; st > 0; st >>= 1) {
        if (tid < st) rd[tid] = fmaxf(rd[tid], rd[tid + st]);
        __syncthreads();
    }
    const float m = rd[0]; __syncthreads();
    float v0 = expf(el[tid] - m), v1 = expf(el[tid + 256] - m);
    rd[tid] = v0 + v1; __syncthreads();
    for (int st = 128; st > 0; st >>= 1) {
        if (tid < st) rd[tid] += rd[tid + st];
        __syncthreads();
    }
    const float inv = 1.0f / rd[0];
    attn[b * 512 + tid] = v0 * inv;
    attn[b * 512 + tid + 256] = v1 * inv;
}

// ---------- context[b,h] = sum_s attn[b,s]*enc[b,s,h]  (atomicAdd partials) ----------
__global__ __launch_bounds__(256) void kContext(
        const float* __restrict__ enc, const float* __restrict__ attn,
        float* __restrict__ ctx) {
    __shared__ float al[64];
    const int tid = threadIdx.x;
    const int b = blockIdx.x >> 3, sc = (blockIdx.x & 7) * 64;
    if (tid < 64) al[tid] = attn[b * 512 + sc + tid];
    __syncthreads();
    float a0 = 0.f, a1 = 0.f;
    for (int s = 0; s < 64; s++) {
        const float* row = enc + (size_t)(b * 512 + sc + s) * 512;
        const float av = al[s];
        a0 += av * row[tid];
        a1 += av * row[tid + 256];
    }
    atomicAdd(&ctx[b * 512 + tid], a0);
    atomicAdd(&ctx[b * 512 + tid + 256], a1);
}

// ---------- combined = tanh([h1|ctx] @ W_comb.T + b_comb) ----------
__global__ __launch_bounds__(256) void kCombined(
        const float* __restrict__ h1, const float* __restrict__ ctx,
        const float* __restrict__ Wcomb, const float* __restrict__ bcomb,
        float* __restrict__ comb) {
    __shared__ float hc[1024];
    const int tid = threadIdx.x;
    const int b = blockIdx.x >> 1, half = blockIdx.x & 1;
    hc[tid] = h1[b * 512 + tid];        hc[tid + 256] = h1[b * 512 + tid + 256];
    hc[512 + tid] = ctx[b * 512 + tid]; hc[512 + tid + 256] = ctx[b * 512 + tid + 256];
    __syncthreads();
    const int j = half * 256 + tid;
    const float4* w4 = (const float4*)(Wcomb + (size_t)j * 1024);
    const float4* x4 = (const float4*)hc;
    float acc = bcomb[j];
    for (int k = 0; k < 256; k++) {
        float4 w = w4[k], xv = x4[k];
        acc += w.x * xv.x + w.y * xv.y + w.z * xv.z + w.w * xv.w;
    }
    comb[b * 512 + j] = tanhf(acc);
}

// ---------- logits[b,v] = combined[b] . W_out[v] + b_out[v]  (f32, k-split x4) ----------
__global__ __launch_bounds__(256) void kLogits(
        const float* __restrict__ comb, const float* __restrict__ Wout,
        const float* __restrict__ bout, float* __restrict__ logits) {
    __shared__ float cl[4][32][64];   // [kq][kk][b] also reused as reduction scratch
    const int tid = threadIdx.x;
    const int vt = tid & 63, kq = tid >> 6;
    const int v = blockIdx.x * 64 + vt;
    float acc[64];
#pragma unroll
    for (int i = 0; i < 64; i++) acc[i] = 0.f;
    for (int kc = 0; kc < 4; kc++) {
        __syncthreads();
        {
            const float4* s4 = (const float4*)(comb + (size_t)vt * 512 + kq * 128 + kc * 32);
#pragma unroll
            for (int qq = 0; qq < 8; qq++) {
                float4 vv = s4[qq];
                cl[kq][qq * 4 + 0][vt] = vv.x; cl[kq][qq * 4 + 1][vt] = vv.y;
                cl[kq][qq * 4 + 2][vt] = vv.z; cl[kq][qq * 4 + 3][vt] = vv.w;
            }
        }
        __syncthreads();
        float wreg[32];
        const float4* w4 = (const float4*)(Wout + (size_t)v * 512 + kq * 128 + kc * 32);
#pragma unroll
        for (int qq = 0; qq < 8; qq++) {
            float4 wv = w4[qq];
            wreg[qq * 4 + 0] = wv.x; wreg[qq * 4 + 1] = wv.y;
            wreg[qq * 4 + 2] = wv.z; wreg[qq * 4 + 3] = wv.w;
        }
#pragma unroll
        for (int kk = 0; kk < 32; kk++) {
            const float wv = wreg[kk];
            const float4* cp = (const float4*)&cl[kq][kk][0];
#pragma unroll
            for (int b4 = 0; b4 < 16; b4++) {
                float4 c4 = cp[b4];
                acc[b4 * 4 + 0] += wv * c4.x; acc[b4 * 4 + 1] += wv * c4.y;
                acc[b4 * 4 + 2] += wv * c4.z; acc[b4 * 4 + 3] += wv * c4.w;
            }
        }
    }
    float* red = &cl[0][0][0];
    __syncthreads();
    if (kq >= 2) {
#pragma unroll
        for (int b = 0; b < 64; b++) red[(kq - 2) * 4096 + vt * 64 + b] = acc[b];
    }
    __syncthreads();
    if (kq < 2) {
#pragma unroll
        for (int b = 0; b < 64; b++) acc[b] += red[kq * 4096 + vt * 64 + b];
    }
    __syncthreads();
    if (kq == 1) {
#pragma unroll
        for (int b = 0; b < 64; b++) red[vt * 64 + b] = acc[b];
    }
    __syncthreads();
    if (kq == 0) {
        const float bo = bout[v];
#pragma unroll
        for (int b = 0; b < 64; b++)
            logits[(size_t)b * 32000 + v] = acc[b] + red[vt * 64 + b] + bo;
    }
}

// ---------- seq-energy GEMM + fused scatter-max ----------
// seq_e[m] = sum_h tanh( (seqs @ W_seqkey.T)[m,h] ) * h1[b,h], then atomicMax into copyenc.
// bf16 MFMA hi/lo split: K = Ah*Bh + Al*Bh + Ah*Bl (~f32 precision).
// v3: MT=128 rows/block -> 256 blocks (1/CU, single round). B-fragment L2 traffic
// drops 1GB -> 256MB (was the 80us bottleneck: HBM idle, MFMA floor 6us).
// A staged hi/lo in LDS in 4 K-chunks of 128 (75.8KB LDS). acc[8][4] => ~200 regs,
// launch_bounds(512,2) for the 256-reg tier (8 waves/CU).
#define ACH 136   // chunk LDS row stride in ushorts: 128 + 8 pad (2-way-max bank aliasing)
__global__ __launch_bounds__(512, 2) void kSeqGemm(
        const float* __restrict__ seqs, const unsigned short* __restrict__ swzh,
        const unsigned short* __restrict__ swzl, const float* __restrict__ h1g,
        const void* __restrict__ mask, const int* __restrict__ extix,
        const int* __restrict__ flag, unsigned int* __restrict__ copyenc) {
    __shared__ unsigned short a_hi[128 * ACH];   // 34816 B
    __shared__ unsigned short a_lo[128 * ACH];   // 34816 B
    __shared__ float h1l[512];
    __shared__ float partf[8][128];
    const int tid = threadIdx.x;
    const int m0 = blockIdx.x * 128;
    const int b = blockIdx.x >> 2;           // 4 blocks per batch row
    const int w = tid >> 6;
    const int lane = tid & 63;
    const int quad = lane >> 4;
    const int c16 = lane & 15;

    h1l[tid] = h1g[b * 512 + tid];

    floatx4 acc[8][4];
    const floatx4 zf = {0.f, 0.f, 0.f, 0.f};
#pragma unroll
    for (int i = 0; i < 8; i++)
#pragma unroll
        for (int j = 0; j < 4; j++) acc[i][j] = zf;

    const size_t boff = (size_t)(w * 64) * 512 + (size_t)lane * 8;
    const unsigned short* bh = swzh + boff;
    const unsigned short* bl = swzl + boff;

    const int srow = tid >> 2, sq = tid & 3;   // staging: 4 threads/row, 32 floats each

    for (int c = 0; c < 4; c++) {
        __syncthreads();   // previous chunk's readers done
        {
            const float* src = seqs + (size_t)(m0 + srow) * 512 + c * 128 + sq * 32;
            unsigned short* dh = &a_hi[srow * ACH + sq * 32];
            unsigned short* dl = &a_lo[srow * ACH + sq * 32];
#pragma unroll
            for (int i = 0; i < 8; i++) {
                float4 v = *(const float4*)(src + i * 4);
                ushort4 hv, lv;
                hv.x = f2bf(v.x); lv.x = f2bf(v.x - bf2f(hv.x));
                hv.y = f2bf(v.y); lv.y = f2bf(v.y - bf2f(hv.y));
                hv.z = f2bf(v.z); lv.z = f2bf(v.z - bf2f(hv.z));
                hv.w = f2bf(v.w); lv.w = f2bf(v.w - bf2f(hv.w));
                *(ushort4*)(dh + i * 4) = hv;
                *(ushort4*)(dl + i * 4) = lv;
            }
        }
        __syncthreads();
#pragma unroll
        for (int kcl = 0; kcl < 4; kcl++) {
            const int kc = c * 4 + kcl;
            bf16x8 bhf[4], blf[4];
#pragma unroll
            for (int nt = 0; nt < 4; nt++) {
                bhf[nt] = *(const bf16x8*)(bh + (size_t)(nt * 16 + kc) * 512);
                blf[nt] = *(const bf16x8*)(bl + (size_t)(nt * 16 + kc) * 512);
            }
#pragma unroll
            for (int ms = 0; ms < 8; ms++) {
                bf16x8 ah = *(const bf16x8*)&a_hi[(ms * 16 + c16) * ACH + kcl * 32 + quad * 8];
                bf16x8 al = *(const bf16x8*)&a_lo[(ms * 16 + c16) * ACH + kcl * 32 + quad * 8];
#pragma unroll
                for (int nt = 0; nt < 4; nt++) {
                    acc[ms][nt] = __builtin_amdgcn_mfma_f32_16x16x32_bf16(
                        ah, bhf[nt], acc[ms][nt], 0, 0, 0);
                    acc[ms][nt] = __builtin_amdgcn_mfma_f32_16x16x32_bf16(
                        al, bhf[nt], acc[ms][nt], 0, 0, 0);
                    acc[ms][nt] = __builtin_amdgcn_mfma_f32_16x16x32_bf16(
                        ah, blf[nt], acc[ms][nt], 0, 0, 0);
                }
            }
        }
    }

    // ---- epilogue: partial over this wave's 64 cols, reduce across waves ----
    float psum[32];
#pragma unroll
    for (int i = 0; i < 32; i++) psum[i] = 0.f;
#pragma unroll
    for (int ms = 0; ms < 8; ms++)
#pragma unroll
        for (int nt = 0; nt < 4; nt++) {
            const float hv = h1l[w * 64 + nt * 16 + c16];
#pragma unroll
            for (int r = 0; r < 4; r++)
                psum[ms * 4 + r] += tanhf(acc[ms][nt][r]) * hv;   // D: row=quad*4+r, col=c16
        }
#pragma unroll
    for (int d = 1; d < 16; d <<= 1)
#pragma unroll
        for (int i = 0; i < 32; i++) psum[i] += __shfl_xor(psum[i], d);
    if (c16 == 0) {
#pragma unroll
        for (int ms = 0; ms < 8; ms++)
#pragma unroll
            for (int r = 0; r < 4; r++)
                partf[w][ms * 16 + quad * 4 + r] = psum[ms * 4 + r];
    }
    __syncthreads();
    if (tid < 128) {
        float s = 0.f;
#pragma unroll
        for (int ww = 0; ww < 8; ww++) s += partf[ww][tid];
        // fused scatter-max (was kScatter)
        const int m = m0 + tid;
        bool mk;
        if (*flag) mk = ((const unsigned char*)mask)[m] != 0;
        else       mk = ((const int*)mask)[m] != 0;
        if (mk) s = 1e-12f;
        const int idx = extix[m];
        atomicMax(&copyenc[(size_t)b * VEXT + idx], enc_f(s));
    }
}

// ---------- log_softmax stage 1: assemble o, write, atomicMax row max ----------
__global__ __launch_bounds__(256) void kFinal1(
        const float* __restrict__ logits, const unsigned int* __restrict__ copyenc,
        float* __restrict__ out0, unsigned int* __restrict__ rmax) {
    __shared__ float rd[4];
    const int tid = threadIdx.x;
    const int b = blockIdx.x >> 4, chunk = blockIdx.x & 15;
    const int base = chunk * 2048 + tid;
    const float* lrow = logits + (size_t)b * 32000;
    const unsigned int* crow = copyenc + (size_t)b * VEXT;
    float* orow = out0 + (size_t)b * VEXT;
    float lm = -3.0e38f;
#pragma unroll
    for (int k = 0; k < 8; k++) {
        const int j = base + k * 256;
        if (j < VEXT) {
            float ext = (j < 32000) ? lrow[j] : 0.0f;
            float cv = dec_f(crow[j]);
            if (cv == -INF_F) cv = 0.0f;
            float o = ext + cv;
            if (o == 0.0f) o = -INF_F;
            orow[j] = o;
            lm = fmaxf(lm, o);
        }
    }
#pragma unroll
    for (int d = 1; d < 64; d <<= 1) lm = fmaxf(lm, __shfl_xor(lm, d));
    if ((tid & 63) == 0) rd[tid >> 6] = lm;
    __syncthreads();
    if (tid == 0) {
        float m = fmaxf(fmaxf(rd[0], rd[1]), fmaxf(rd[2], rd[3]));
        atomicMax(&rmax[b], enc_f(m));
    }
}

// ---------- log_softmax stage 2: partial exp-sums ----------
__global__ __launch_bounds__(256) void kFinal2(
        const float* __restrict__ out0, const unsigned int* __restrict__ rmax,
        float* __restrict__ rsum) {
    __shared__ float rd[4];
    const int tid = threadIdx.x;
    const int b = blockIdx.x >> 4, chunk = blockIdx.x & 15;
    const int base = chunk * 2048 + tid;
    const float* orow = out0 + (size_t)b * VEXT;
    const float m = dec_f(rmax[b]);
    float s = 0.f;
#pragma unroll
    for (int k = 0; k < 8; k++) {
        const int j = base + k * 256;
        if (j < VEXT) s += expf(orow[j] - m);
    }
#pragma unroll
    for (int d = 1; d < 64; d <<= 1) s += __shfl_xor(s, d);
    if ((tid & 63) == 0) rd[tid >> 6] = s;
    __syncthreads();
    if (tid == 0) atomicAdd(&rsum[b], rd[0] + rd[1] + rd[2] + rd[3]);
}

// ---------- log_softmax stage 3: subtract lse ----------
__global__ __launch_bounds__(256) void kFinal3(
        float* __restrict__ out0, const unsigned int* __restrict__ rmax,
        const float* __restrict__ rsum) {
    const int tid = threadIdx.x;
    const int b = blockIdx.x >> 4, chunk = blockIdx.x & 15;
    const int base = chunk * 2048 + tid;
    float* orow = out0 + (size_t)b * VEXT;
    const float lse = dec_f(rmax[b]) + logf(rsum[b]);
#pragma unroll
    for (int k = 0; k < 8; k++) {
        const int j = base + k * 256;
        if (j < VEXT) orow[j] -= lse;
    }
}

extern "C" void kernel_launch(void* const* d_in, const int* in_sizes, int n_in,
                              void* d_out, int out_size, void* d_ws, size_t ws_size,
                              hipStream_t stream) {
    const int*   ids   = (const int*)d_in[0];
    const float* pctx  = (const float*)d_in[1];
    const float* h0    = (const float*)d_in[2];
    const float* c0    = (const float*)d_in[3];
    const float* enc   = (const float*)d_in[4];
    const float* seqs  = (const float*)d_in[5];
    const void*  mask  = d_in[6];
    const int*   extix = (const int*)d_in[7];
    const float* embed = (const float*)d_in[8];
    const float* Wred  = (const float*)d_in[9];
    const float* bred  = (const float*)d_in[10];
    const float* Wkey  = (const float*)d_in[11];
    const float* bkey  = (const float*)d_in[12];
    const float* Wcomb = (const float*)d_in[13];
    const float* bcomb = (const float*)d_in[14];
    const float* Wseqk = (const float*)d_in[15];
    const float* Wih   = (const float*)d_in[16];
    const float* Whh   = (const float*)d_in[17];
    const float* bih   = (const float*)d_in[18];
    const float* bhh   = (const float*)d_in[19];
    const float* Wout  = (const float*)d_in[20];
    const float* bout  = (const float*)d_in[21];
    (void)in_sizes; (void)n_in; (void)out_size; (void)ws_size;

    float* out = (float*)d_out;
    float* ws = (float*)d_ws;
    int* flag = (int*)ws;
    float* xws = ws + WS_X;
    float* gatesws = ws + WS_GATES;
    float* qws = ws + WS_Q;
    float* kbws = ws + WS_KB;
    float* enws = ws + WS_EN;
    float* combws = ws + WS_COMB;
    unsigned short* wskh = (unsigned short*)(ws + WS_WSKBF);
    float* logitsws = ws + WS_LOGITS;
    unsigned short* wskl = (unsigned short*)(ws + WS_LOGITS);  // overlay; dead before kLogits
    unsigned int* copyenc = (unsigned int*)(ws + WS_COPY);
    unsigned int* rmax = (unsigned int*)(ws + WS_RMAX);
    float* rsum = ws + WS_RSUM;

    kDetect<<<1, 256, 0, stream>>>((const unsigned int*)mask, flag);
    kConvertW<<<128, 256, 0, stream>>>(Wseqk, wskh, wskl);
    kFillCopy<<<2004, 256, 0, stream>>>(copyenc, rmax, rsum);
    kEmbedReduce<<<128, 256, 0, stream>>>(ids, embed, pctx, Wred, bred, xws);
    kGates<<<512, 256, 0, stream>>>(xws, h0, Wih, Whh, bih, bhh, gatesws);
    kLstm<<<128, 256, 0, stream>>>(gatesws, c0, out + OFF_H1, out + OFF_C1);
    // seq-energy GEMM (+fused scatter) before kLogits so the W_lo overlay is legal
    kSeqGemm<<<256, 512, 0, stream>>>(seqs, wskh, wskl, out + OFF_H1,
                                      mask, extix, flag, copyenc);
    kQ<<<128, 256, 0, stream>>>(out + OFF_H1, Wkey, bkey, qws, kbws);
    kEnergies<<<256, 256, 0, stream>>>(enc, qws, kbws, enws);
    kSoftmax<<<64, 256, 0, stream>>>(enws, out + OFF_ATTN);
    hipMemsetAsync(out + OFF_CTX, 0, (size_t)B_N * H_N * sizeof(float), stream);
    kContext<<<512, 256, 0, stream>>>(enc, out + OFF_ATTN, out + OFF_CTX);
    kCombined<<<128, 256, 0, stream>>>(out + OFF_H1, out + OFF_CTX, Wcomb, bcomb, combws);
    kLogits<<<500, 256, 0, stream>>>(combws, Wout, bout, logitsws);
    kFinal1<<<1024, 256, 0, stream>>>(logitsws, copyenc, out + OFF_OUT0, rmax);
    kFinal2<<<1024, 256, 0, stream>>>(out + OFF_OUT0, rmax, rsum);
    kFinal3<<<1024, 256, 0, stream>>>(out + OFF_OUT0, rmax, rsum);
}

// Round 5
// 591.648 us; speedup vs baseline: 1.0101x; 1.0101x over previous
//
#include <hip/hip_runtime.h>
#include <math.h>

#define B_N    64
#define H_N    512
#define V_N    32000
#define S_N    512
#define VEXT   32050
#define INF_F  1000000000000.0f

typedef __attribute__((ext_vector_type(4))) float floatx4;
typedef __attribute__((ext_vector_type(8))) __bf16 bf16x8;

// ---- output layout (floats) ----
#define OFF_OUT0 0
#define OFF_CTX  (B_N * VEXT)                 // 2051200
#define OFF_H1   (OFF_CTX + B_N * H_N)        // 2083968
#define OFF_C1   (OFF_H1 + B_N * H_N)        // 2116736
#define OFF_ATTN (OFF_C1 + B_N * H_N)        // 2149504

// ---- workspace layout (32-bit words) ----
#define WS_FLAG   0
#define WS_X      16
#define WS_GATES  (WS_X + B_N * H_N)                  // 32784
#define WS_Q      (WS_GATES + B_N * 4 * H_N)          // 163856
#define WS_KB     (WS_Q + B_N * H_N)                  // 196624
#define WS_EN     (WS_KB + B_N)                       // 196688
#define WS_COMB   (WS_EN + B_N * S_N)                 // 229456
#define WS_SEQE   (WS_COMB + B_N * H_N)               // 262224 (unused; kept for layout)
#define WS_WSKBF  (WS_SEQE + B_N * S_N)               // 294992 (512*512 ushort, swizzled, HI part)
#define WS_LOGITS (WS_WSKBF + (H_N * H_N) / 2)        // 426064
// W_lo (512*512 ushort = 131072 words) OVERLAYS the head of WS_LOGITS.
// Legal because kSeqGemm (reader) completes before kLogits (writer) on the stream.
#define WS_COPY   (WS_LOGITS + B_N * V_N)             // 2474064
#define WS_RMAX   (WS_COPY + B_N * VEXT)              // 4525264 (64 uints)
#define WS_RSUM   (WS_RMAX + B_N)                     // +64 floats

__device__ __forceinline__ float sigm(float x) { return 1.0f / (1.0f + expf(-x)); }

__device__ __forceinline__ unsigned short f2bf(float f) {
    unsigned u = __float_as_uint(f);
    u += 0x7fffu + ((u >> 16) & 1u);   // round-to-nearest-even
    return (unsigned short)(u >> 16);
}
__device__ __forceinline__ float bf2f(unsigned short h) {
    return __uint_as_float(((unsigned)h) << 16);
}

// order-preserving float<->uint encode for atomicMax-based scatter-max
__device__ __forceinline__ unsigned enc_f(float f) {
    unsigned u = __float_as_uint(f);
    return (u & 0x80000000u) ? ~u : (u | 0x80000000u);
}
__device__ __forceinline__ float dec_f(unsigned e) {
    unsigned u = (e & 0x80000000u) ? (e & 0x7fffffffu) : ~e;
    return __uint_as_float(u);
}

// ---------- fused prologue: detect mask width | convert W hi/lo | fill copy | zero ctx ----
// blocks [0]           : mask storage-width detect -> flag
// blocks [1, 129)      : W_seqkey f32 -> bf16 hi/lo, pre-swizzled B-fragment order
// blocks [129, 2133)   : copyenc = enc(-INF); first block also inits rmax/rsum
// blocks [2133, 2165)  : ctx = 0
__global__ __launch_bounds__(256) void kPre(
        const unsigned int* __restrict__ m, int* __restrict__ flag,
        const float* __restrict__ W, unsigned short* __restrict__ swzh,
        unsigned short* __restrict__ swzl, unsigned int* __restrict__ copyenc,
        unsigned int* __restrict__ rmax, float* __restrict__ rsum,
        float* __restrict__ ctx) {
    const int bx = blockIdx.x, tid = threadIdx.x;
    if (bx == 0) {
        __shared__ int any;
        if (tid == 0) any = 0;
        __syncthreads();
        int loc = 0;
        for (int i = tid; i < 8192; i += 256) loc |= (m[i] > 1u) ? 1 : 0;
        if (loc) any = 1;
        __syncthreads();
        if (tid == 0) *flag = any;   // 1 => byte storage, 0 => int32 storage
    } else if (bx < 129) {
        // layout: swz[((t*16+kc)*64+lane)*8 + j] = W[(t*16+(lane&15))*512 + kc*32 + (lane>>4)*8 + j]
        const int g = (bx - 1) * 256 + tid;            // 32768 threads, 8 elems each
        const int t = g >> 10, kc = (g >> 6) & 15, lane = g & 63;
        const int r = t * 16 + (lane & 15);
        const int k = kc * 32 + (lane >> 4) * 8;
        const float* src = W + (size_t)r * 512 + k;
        ushort4 h0, h1, l0, l1;
        const float4 v0 = *(const float4*)(src);
        const float4 v1 = *(const float4*)(src + 4);
        h0.x = f2bf(v0.x); l0.x = f2bf(v0.x - bf2f(h0.x));
        h0.y = f2bf(v0.y); l0.y = f2bf(v0.y - bf2f(h0.y));
        h0.z = f2bf(v0.z); l0.z = f2bf(v0.z - bf2f(h0.z));
        h0.w = f2bf(v0.w); l0.w = f2bf(v0.w - bf2f(h0.w));
        h1.x = f2bf(v1.x); l1.x = f2bf(v1.x - bf2f(h1.x));
        h1.y = f2bf(v1.y); l1.y = f2bf(v1.y - bf2f(h1.y));
        h1.z = f2bf(v1.z); l1.z = f2bf(v1.z - bf2f(h1.z));
        h1.w = f2bf(v1.w); l1.w = f2bf(v1.w - bf2f(h1.w));
        *(ushort4*)(swzh + (size_t)g * 8) = h0;
        *(ushort4*)(swzh + (size_t)g * 8 + 4) = h1;
        *(ushort4*)(swzl + (size_t)g * 8) = l0;
        *(ushort4*)(swzl + (size_t)g * 8 + 4) = l1;
    } else if (bx < 2133) {
        const int fb = bx - 129;
        const unsigned NE = enc_f(-INF_F);
        if (fb == 0 && tid < B_N) {
            rmax[tid] = 0u;
            rsum[tid] = 0.0f;
        }
        int i0 = (fb * 256 + tid) * 4;
#pragma unroll
        for (int k = 0; k < 4; k++) {
            int i = i0 + k;
            if (i < B_N * VEXT) copyenc[i] = NE;
        }
    } else {
        const int zb = bx - 2133;                      // 32 blocks zero 32768 floats
        const float4 z4 = {0.f, 0.f, 0.f, 0.f};
        *(float4*)(ctx + (size_t)(zb * 256 + tid) * 4) = z4;
    }
}

// ---------- x = [embed[id] | prev_context] @ W_reduce.T + b_reduce ----------
__global__ __launch_bounds__(256) void kEmbedReduce(
        const int* __restrict__ ids, const float* __restrict__ embed,
        const float* __restrict__ pctx, const float* __restrict__ Wred,
        const float* __restrict__ bred, float* __restrict__ x) {
    __shared__ float xc[1024];
    const int tid = threadIdx.x;
    const int b = blockIdx.x >> 1, half = blockIdx.x & 1;
    const float* er = embed + (size_t)ids[b] * 512;
    xc[tid] = er[tid];               xc[tid + 256] = er[tid + 256];
    xc[512 + tid] = pctx[b * 512 + tid]; xc[512 + tid + 256] = pctx[b * 512 + tid + 256];
    __syncthreads();
    const int j = half * 256 + tid;
    const float4* w4 = (const float4*)(Wred + (size_t)j * 1024);
    const float4* x4 = (const float4*)xc;
    float acc = bred[j];
    for (int k = 0; k < 256; k++) {
        float4 w = w4[k], xv = x4[k];
        acc += w.x * xv.x + w.y * xv.y + w.z * xv.z + w.w * xv.w;
    }
    x[b * 512 + j] = acc;
}

// ---------- gates = x @ W_ih.T + h0 @ W_hh.T + b_ih + b_hh ----------
__global__ __launch_bounds__(256) void kGates(
        const float* __restrict__ x, const float* __restrict__ h0,
        const float* __restrict__ Wih, const float* __restrict__ Whh,
        const float* __restrict__ bih, const float* __restrict__ bhh,
        float* __restrict__ gates) {
    __shared__ float xl[512], hl[512];
    const int tid = threadIdx.x;
    const int b = blockIdx.x >> 3, part = blockIdx.x & 7;
    xl[tid] = x[b * 512 + tid];  xl[tid + 256] = x[b * 512 + tid + 256];
    hl[tid] = h0[b * 512 + tid]; hl[tid + 256] = h0[b * 512 + tid + 256];
    __syncthreads();
    const int j = part * 256 + tid;
    const float4* wi4 = (const float4*)(Wih + (size_t)j * 512);
    const float4* wh4 = (const float4*)(Whh + (size_t)j * 512);
    const float4* x4 = (const float4*)xl;
    const float4* h4 = (const float4*)hl;
    float acc = bih[j] + bhh[j];
    for (int k = 0; k < 128; k++) {
        float4 w = wi4[k], xv = x4[k];
        acc += w.x * xv.x + w.y * xv.y + w.z * xv.z + w.w * xv.w;
    }
    for (int k = 0; k < 128; k++) {
        float4 w = wh4[k], hv = h4[k];
        acc += w.x * hv.x + w.y * hv.y + w.z * hv.z + w.w * hv.w;
    }
    gates[(size_t)b * 2048 + j] = acc;
}

// ---------- LSTM elementwise (PyTorch i,f,g,o order) ----------
__global__ __launch_bounds__(256) void kLstm(
        const float* __restrict__ gates, const float* __restrict__ c0,
        float* __restrict__ h1o, float* __restrict__ c1o) {
    const int idx = blockIdx.x * 256 + threadIdx.x;  // < 32768
    const int b = idx >> 9, j = idx & 511;
    const float gi = gates[(size_t)b * 2048 + j];
    const float gf = gates[(size_t)b * 2048 + 512 + j];
    const float gg = gates[(size_t)b * 2048 + 1024 + j];
    const float go = gates[(size_t)b * 2048 + 1536 + j];
    const float cp = c0[idx];
    const float c1 = sigm(gf) * cp + sigm(gi) * tanhf(gg);
    const float h1 = sigm(go) * tanhf(c1);
    h1o[idx] = h1;
    c1o[idx] = c1;
}

// ---------- q[b,k] = sum_h h1[b,h]*W_key[h,k]; kb[b] = b_key . h1[b] ----------
__global__ __launch_bounds__(256) void kQ(
        const float* __restrict__ h1, const float* __restrict__ Wkey,
        const float* __restrict__ bkey, float* __restrict__ q, float* __restrict__ kb) {
    __shared__ float hl[512];
    __shared__ float rd[256];
    const int tid = threadIdx.x;
    const int b = blockIdx.x >> 1, half = blockIdx.x & 1;
    hl[tid] = h1[b * 512 + tid]; hl[tid + 256] = h1[b * 512 + tid + 256];
    __syncthreads();
    const int k = half * 256 + tid;
    float acc = 0.f;
#pragma unroll 4
    for (int h = 0; h < 512; h++) acc += hl[h] * Wkey[(size_t)h * 512 + k];
    q[b * 512 + k] = acc;
    if (half == 0) {   // block-uniform branch
        float p = bkey[tid] * hl[tid] + bkey[tid + 256] * hl[tid + 256];
        rd[tid] = p; __syncthreads();
        for (int st = 128; st > 0; st >>= 1) {
            if (tid < st) rd[tid] += rd[tid + st];
            __syncthreads();
        }
        if (tid == 0) kb[b] = rd[0];
    }
}

// ---------- energies[b,s] = enc[b,s,:].q[b] + kb[b]; mask rows summing to 0 ----------
__global__ __launch_bounds__(256) void kEnergies(
        const float* __restrict__ enc, const float* __restrict__ q,
        const float* __restrict__ kb, float* __restrict__ energ) {
    __shared__ float ql[512];
    __shared__ float pe[256], ps[256];
    const int tid = threadIdx.x;
    const int b = blockIdx.x >> 2;
    const int sc = (blockIdx.x & 3) * 128;
    ql[tid] = q[b * 512 + tid]; ql[tid + 256] = q[b * 512 + tid + 256];
    __syncthreads();
    const int r = tid & 127, hi = tid >> 7;
    const float4* row4 = (const float4*)(enc + (size_t)(b * 512 + sc + r) * 512 + hi * 256);
    const float4* q4 = (const float4*)(ql + hi * 256);
    float e = 0.f, ssum = 0.f;
#pragma unroll 4
    for (int k = 0; k < 64; k++) {
        float4 ev = row4[k], qv = q4[k];
        e += ev.x * qv.x + ev.y * qv.y + ev.z * qv.z + ev.w * qv.w;
        ssum += ev.x + ev.y + ev.z + ev.w;
    }
    pe[tid] = e; ps[tid] = ssum;
    __syncthreads();
    if (tid < 128) {
        float ee = pe[tid] + pe[tid + 128] + kb[b];
        float sm = ps[tid] + ps[tid + 128];
        if (sm == 0.0f) ee = 1e-12f;        // enc_mask semantics
        energ[b * 512 + sc + tid] = ee;
    }
}

// ---------- softmax over S per b ----------
__global__ __launch_bounds__(256) void kSoftmax(
        const float* __restrict__ energ, float* __restrict__ attn) {
    __shared__ float el[512];
    __shared__ float rd[256];
    const int tid = threadIdx.x, b = blockIdx.x;
    el[tid] = energ[b * 512 + tid]; el[tid + 256] = energ[b * 512 + tid + 256];
    __syncthreads();
    rd[tid] = fmaxf(el[tid], el[tid + 256]); __syncthreads();
    for (int st = 128; st > 0; st >>= 1) {
        if (tid < st) rd[tid] = fmaxf(rd[tid], rd[tid + st]);
        __syncthreads();
    }
    const float m = rd[0]; __syncthreads();
    float v0 = expf(el[tid] - m), v1 = expf(el[tid + 256] - m);
    rd[tid] = v0 + v1; __syncthreads();
    for (int st = 128; st > 0; st >>= 1) {
        if (tid < st) rd[tid] += rd[tid + st];
        __syncthreads();
    }
    const float inv = 1.0f / rd[0];
    attn[b * 512 + tid] = v0 * inv;
    attn[b * 512 + tid + 256] = v1 * inv;
}

// ---------- context[b,h] = sum_s attn[b,s]*enc[b,s,h]  (atomicAdd partials) ----------
__global__ __launch_bounds__(256) void kContext(
        const float* __restrict__ enc, const float* __restrict__ attn,
        float* __restrict__ ctx) {
    __shared__ float al[64];
    const int tid = threadIdx.x;
    const int b = blockIdx.x >> 3, sc = (blockIdx.x & 7) * 64;
    if (tid < 64) al[tid] = attn[b * 512 + sc + tid];
    __syncthreads();
    float a0 = 0.f, a1 = 0.f;
    for (int s = 0; s < 64; s++) {
        const float* row = enc + (size_t)(b * 512 + sc + s) * 512;
        const float av = al[s];
        a0 += av * row[tid];
        a1 += av * row[tid + 256];
    }
    atomicAdd(&ctx[b * 512 + tid], a0);
    atomicAdd(&ctx[b * 512 + tid + 256], a1);
}

// ---------- combined = tanh([h1|ctx] @ W_comb.T + b_comb) ----------
__global__ __launch_bounds__(256) void kCombined(
        const float* __restrict__ h1, const float* __restrict__ ctx,
        const float* __restrict__ Wcomb, const float* __restrict__ bcomb,
        float* __restrict__ comb) {
    __shared__ float hc[1024];
    const int tid = threadIdx.x;
    const int b = blockIdx.x >> 1, half = blockIdx.x & 1;
    hc[tid] = h1[b * 512 + tid];        hc[tid + 256] = h1[b * 512 + tid + 256];
    hc[512 + tid] = ctx[b * 512 + tid]; hc[512 + tid + 256] = ctx[b * 512 + tid + 256];
    __syncthreads();
    const int j = half * 256 + tid;
    const float4* w4 = (const float4*)(Wcomb + (size_t)j * 1024);
    const float4* x4 = (const float4*)hc;
    float acc = bcomb[j];
    for (int k = 0; k < 256; k++) {
        float4 w = w4[k], xv = x4[k];
        acc += w.x * xv.x + w.y * xv.y + w.z * xv.z + w.w * xv.w;
    }
    comb[b * 512 + j] = tanhf(acc);
}

// ---------- logits[b,v] = combined[b] . W_out[v] + b_out[v]  (f32, k-split x4) ----------
__global__ __launch_bounds__(256) void kLogits(
        const float* __restrict__ comb, const float* __restrict__ Wout,
        const float* __restrict__ bout, float* __restrict__ logits) {
    __shared__ float cl[4][32][64];   // [kq][kk][b] also reused as reduction scratch
    const int tid = threadIdx.x;
    const int vt = tid & 63, kq = tid >> 6;
    const int v = blockIdx.x * 64 + vt;
    float acc[64];
#pragma unroll
    for (int i = 0; i < 64; i++) acc[i] = 0.f;
    for (int kc = 0; kc < 4; kc++) {
        __syncthreads();
        {
            const float4* s4 = (const float4*)(comb + (size_t)vt * 512 + kq * 128 + kc * 32);
#pragma unroll
            for (int qq = 0; qq < 8; qq++) {
                float4 vv = s4[qq];
                cl[kq][qq * 4 + 0][vt] = vv.x; cl[kq][qq * 4 + 1][vt] = vv.y;
                cl[kq][qq * 4 + 2][vt] = vv.z; cl[kq][qq * 4 + 3][vt] = vv.w;
            }
        }
        __syncthreads();
        float wreg[32];
        const float4* w4 = (const float4*)(Wout + (size_t)v * 512 + kq * 128 + kc * 32);
#pragma unroll
        for (int qq = 0; qq < 8; qq++) {
            float4 wv = w4[qq];
            wreg[qq * 4 + 0] = wv.x; wreg[qq * 4 + 1] = wv.y;
            wreg[qq * 4 + 2] = wv.z; wreg[qq * 4 + 3] = wv.w;
        }
#pragma unroll
        for (int kk = 0; kk < 32; kk++) {
            const float wv = wreg[kk];
            const float4* cp = (const float4*)&cl[kq][kk][0];
#pragma unroll
            for (int b4 = 0; b4 < 16; b4++) {
                float4 c4 = cp[b4];
                acc[b4 * 4 + 0] += wv * c4.x; acc[b4 * 4 + 1] += wv * c4.y;
                acc[b4 * 4 + 2] += wv * c4.z; acc[b4 * 4 + 3] += wv * c4.w;
            }
        }
    }
    float* red = &cl[0][0][0];
    __syncthreads();
    if (kq >= 2) {
#pragma unroll
        for (int b = 0; b < 64; b++) red[(kq - 2) * 4096 + vt * 64 + b] = acc[b];
    }
    __syncthreads();
    if (kq < 2) {
#pragma unroll
        for (int b = 0; b < 64; b++) acc[b] += red[kq * 4096 + vt * 64 + b];
    }
    __syncthreads();
    if (kq == 1) {
#pragma unroll
        for (int b = 0; b < 64; b++) red[vt * 64 + b] = acc[b];
    }
    __syncthreads();
    if (kq == 0) {
        const float bo = bout[v];
#pragma unroll
        for (int b = 0; b < 64; b++)
            logits[(size_t)b * 32000 + v] = acc[b] + red[vt * 64 + b] + bo;
    }
}

// ---------- seq-energy GEMM + fused scatter-max (round-3 verified body) ----------
// seq_e[m] = sum_h tanh( (seqs @ W_seqkey.T)[m,h] ) * h1[b,h], then atomicMax into copyenc.
// bf16 MFMA hi/lo split: K = Ah*Bh + Al*Bh + Ah*Bl (~f32 precision).
// MT=128 rows/block -> 256 blocks (1/CU). A staged hi/lo in LDS in 4 K-chunks of 128.
#define ACH 136   // chunk LDS row stride in ushorts: 128 + 8 pad
__global__ __launch_bounds__(512, 2) void kSeqGemm(
        const float* __restrict__ seqs, const unsigned short* __restrict__ swzh,
        const unsigned short* __restrict__ swzl, const float* __restrict__ h1g,
        const void* __restrict__ mask, const int* __restrict__ extix,
        const int* __restrict__ flag, unsigned int* __restrict__ copyenc) {
    __shared__ unsigned short a_hi[128 * ACH];   // 34816 B
    __shared__ unsigned short a_lo[128 * ACH];   // 34816 B
    __shared__ float h1l[512];
    __shared__ float partf[8][128];
    const int tid = threadIdx.x;
    const int m0 = blockIdx.x * 128;
    const int b = blockIdx.x >> 2;           // 4 blocks per batch row
    const int w = tid >> 6;
    const int lane = tid & 63;
    const int quad = lane >> 4;
    const int c16 = lane & 15;

    h1l[tid] = h1g[b * 512 + tid];

    floatx4 acc[8][4];
    const floatx4 zf = {0.f, 0.f, 0.f, 0.f};
#pragma unroll
    for (int i = 0; i < 8; i++)
#pragma unroll
        for (int j = 0; j < 4; j++) acc[i][j] = zf;

    const size_t boff = (size_t)(w * 64) * 512 + (size_t)lane * 8;
    const unsigned short* bh = swzh + boff;
    const unsigned short* bl = swzl + boff;

    // staging geometry: 4 threads/row, 32 floats each per chunk
    const int srow = tid >> 2, sq = tid & 3;

    for (int c = 0; c < 4; c++) {
        __syncthreads();   // previous chunk's readers done
        {
            const float* src = seqs + (size_t)(m0 + srow) * 512 + c * 128 + sq * 32;
            unsigned short* dh = &a_hi[srow * ACH + sq * 32];
            unsigned short* dl = &a_lo[srow * ACH + sq * 32];
#pragma unroll
            for (int i = 0; i < 8; i++) {
                float4 v = *(const float4*)(src + i * 4);
                ushort4 hv, lv;
                hv.x = f2bf(v.x); lv.x = f2bf(v.x - bf2f(hv.x));
                hv.y = f2bf(v.y); lv.y = f2bf(v.y - bf2f(hv.y));
                hv.z = f2bf(v.z); lv.z = f2bf(v.z - bf2f(hv.z));
                hv.w = f2bf(v.w); lv.w = f2bf(v.w - bf2f(hv.w));
                *(ushort4*)(dh + i * 4) = hv;
                *(ushort4*)(dl + i * 4) = lv;
            }
        }
        __syncthreads();
#pragma unroll
        for (int kcl = 0; kcl < 4; kcl++) {
            const int kc = c * 4 + kcl;
            bf16x8 bhf[4], blf[4];
#pragma unroll
            for (int nt = 0; nt < 4; nt++) {
                bhf[nt] = *(const bf16x8*)(bh + (size_t)(nt * 16 + kc) * 512);
                blf[nt] = *(const bf16x8*)(bl + (size_t)(nt * 16 + kc) * 512);
            }
#pragma unroll
            for (int ms = 0; ms < 8; ms++) {
                bf16x8 ah = *(const bf16x8*)&a_hi[(ms * 16 + c16) * ACH + kcl * 32 + quad * 8];
                bf16x8 al = *(const bf16x8*)&a_lo[(ms * 16 + c16) * ACH + kcl * 32 + quad * 8];
#pragma unroll
                for (int nt = 0; nt < 4; nt++) {
                    acc[ms][nt] = __builtin_amdgcn_mfma_f32_16x16x32_bf16(
                        ah, bhf[nt], acc[ms][nt], 0, 0, 0);
                    acc[ms][nt] = __builtin_amdgcn_mfma_f32_16x16x32_bf16(
                        al, bhf[nt], acc[ms][nt], 0, 0, 0);
                    acc[ms][nt] = __builtin_amdgcn_mfma_f32_16x16x32_bf16(
                        ah, blf[nt], acc[ms][nt], 0, 0, 0);
                }
            }
        }
    }

    // ---- epilogue: partial over this wave's 64 cols, reduce across waves ----
    float psum[32];
#pragma unroll
    for (int i = 0; i < 32; i++) psum[i] = 0.f;
#pragma unroll
    for (int ms = 0; ms < 8; ms++)
#pragma unroll
        for (int nt = 0; nt < 4; nt++) {
            const float hv = h1l[w * 64 + nt * 16 + c16];
#pragma unroll
            for (int r = 0; r < 4; r++)
                psum[ms * 4 + r] += tanhf(acc[ms][nt][r]) * hv;   // D: row=quad*4+r, col=c16
        }
#pragma unroll
    for (int d = 1; d < 16; d <<= 1)
#pragma unroll
        for (int i = 0; i < 32; i++) psum[i] += __shfl_xor(psum[i], d);
    if (c16 == 0) {
#pragma unroll
        for (int ms = 0; ms < 8; ms++)
#pragma unroll
            for (int r = 0; r < 4; r++)
                partf[w][ms * 16 + quad * 4 + r] = psum[ms * 4 + r];
    }
    __syncthreads();
    if (tid < 128) {
        float s = 0.f;
#pragma unroll
        for (int ww = 0; ww < 8; ww++) s += partf[ww][tid];
        // fused scatter-max (was kScatter)
        const int m = m0 + tid;
        bool mk;
        if (*flag) mk = ((const unsigned char*)mask)[m] != 0;
        else       mk = ((const int*)mask)[m] != 0;
        if (mk) s = 1e-12f;
        const int idx = extix[m];
        atomicMax(&copyenc[(size_t)b * VEXT + idx], enc_f(s));
    }
}

// ---------- log_softmax stage 1: assemble o, write, atomicMax row max ----------
__global__ __launch_bounds__(256) void kFinal1(
        const float* __restrict__ logits, const unsigned int* __restrict__ copyenc,
        float* __restrict__ out0, unsigned int* __restrict__ rmax) {
    __shared__ float rd[4];
    const int tid = threadIdx.x;
    const int b = blockIdx.x >> 4, chunk = blockIdx.x & 15;
    const int base = chunk * 2048 + tid;
    const float* lrow = logits + (size_t)b * 32000;
    const unsigned int* crow = copyenc + (size_t)b * VEXT;
    float* orow = out0 + (size_t)b * VEXT;
    float lm = -3.0e38f;
#pragma unroll
    for (int k = 0; k < 8; k++) {
        const int j = base + k * 256;
        if (j < VEXT) {
            float ext = (j < 32000) ? lrow[j] : 0.0f;
            float cv = dec_f(crow[j]);
            if (cv == -INF_F) cv = 0.0f;
            float o = ext + cv;
            if (o == 0.0f) o = -INF_F;
            orow[j] = o;
            lm = fmaxf(lm, o);
        }
    }
#pragma unroll
    for (int d = 1; d < 64; d <<= 1) lm = fmaxf(lm, __shfl_xor(lm, d));
    if ((tid & 63) == 0) rd[tid >> 6] = lm;
    __syncthreads();
    if (tid == 0) {
        float m = fmaxf(fmaxf(rd[0], rd[1]), fmaxf(rd[2], rd[3]));
        atomicMax(&rmax[b], enc_f(m));
    }
}

// ---------- log_softmax stage 2: partial exp-sums ----------
__global__ __launch_bounds__(256) void kFinal2(
        const float* __restrict__ out0, const unsigned int* __restrict__ rmax,
        float* __restrict__ rsum) {
    __shared__ float rd[4];
    const int tid = threadIdx.x;
    const int b = blockIdx.x >> 4, chunk = blockIdx.x & 15;
    const int base = chunk * 2048 + tid;
    const float* orow = out0 + (size_t)b * VEXT;
    const float m = dec_f(rmax[b]);
    float s = 0.f;
#pragma unroll
    for (int k = 0; k < 8; k++) {
        const int j = base + k * 256;
        if (j < VEXT) s += expf(orow[j] - m);
    }
#pragma unroll
    for (int d = 1; d < 64; d <<= 1) s += __shfl_xor(s, d);
    if ((tid & 63) == 0) rd[tid >> 6] = s;
    __syncthreads();
    if (tid == 0) atomicAdd(&rsum[b], rd[0] + rd[1] + rd[2] + rd[3]);
}

// ---------- log_softmax stage 3: subtract lse ----------
__global__ __launch_bounds__(256) void kFinal3(
        float* __restrict__ out0, const unsigned int* __restrict__ rmax,
        const float* __restrict__ rsum) {
    const int tid = threadIdx.x;
    const int b = blockIdx.x >> 4, chunk = blockIdx.x & 15;
    const int base = chunk * 2048 + tid;
    float* orow = out0 + (size_t)b * VEXT;
    const float lse = dec_f(rmax[b]) + logf(rsum[b]);
#pragma unroll
    for (int k = 0; k < 8; k++) {
        const int j = base + k * 256;
        if (j < VEXT) orow[j] -= lse;
    }
}

extern "C" void kernel_launch(void* const* d_in, const int* in_sizes, int n_in,
                              void* d_out, int out_size, void* d_ws, size_t ws_size,
                              hipStream_t stream) {
    const int*   ids   = (const int*)d_in[0];
    const float* pctx  = (const float*)d_in[1];
    const float* h0    = (const float*)d_in[2];
    const float* c0    = (const float*)d_in[3];
    const float* enc   = (const float*)d_in[4];
    const float* seqs  = (const float*)d_in[5];
    const void*  mask  = d_in[6];
    const int*   extix = (const int*)d_in[7];
    const float* embed = (const float*)d_in[8];
    const float* Wred  = (const float*)d_in[9];
    const float* bred  = (const float*)d_in[10];
    const float* Wkey  = (const float*)d_in[11];
    const float* bkey  = (const float*)d_in[12];
    const float* Wcomb = (const float*)d_in[13];
    const float* bcomb = (const float*)d_in[14];
    const float* Wseqk = (const float*)d_in[15];
    const float* Wih   = (const float*)d_in[16];
    const float* Whh   = (const float*)d_in[17];
    const float* bih   = (const float*)d_in[18];
    const float* bhh   = (const float*)d_in[19];
    const float* Wout  = (const float*)d_in[20];
    const float* bout  = (const float*)d_in[21];
    (void)in_sizes; (void)n_in; (void)out_size; (void)ws_size;

    float* out = (float*)d_out;
    float* ws = (float*)d_ws;
    int* flag = (int*)ws;
    float* xws = ws + WS_X;
    float* gatesws = ws + WS_GATES;
    float* qws = ws + WS_Q;
    float* kbws = ws + WS_KB;
    float* enws = ws + WS_EN;
    float* combws = ws + WS_COMB;
    unsigned short* wskh = (unsigned short*)(ws + WS_WSKBF);
    float* logitsws = ws + WS_LOGITS;
    unsigned short* wskl = (unsigned short*)(ws + WS_LOGITS);  // overlay; dead before kLogits
    unsigned int* copyenc = (unsigned int*)(ws + WS_COPY);
    unsigned int* rmax = (unsigned int*)(ws + WS_RMAX);
    float* rsum = ws + WS_RSUM;

    // fused prologue (detect + convertW + fillCopy + ctx zero): 4 launches -> 1
    kPre<<<2165, 256, 0, stream>>>((const unsigned int*)mask, flag, Wseqk, wskh, wskl,
                                   copyenc, rmax, rsum, out + OFF_CTX);
    kEmbedReduce<<<128, 256, 0, stream>>>(ids, embed, pctx, Wred, bred, xws);
    kGates<<<512, 256, 0, stream>>>(xws, h0, Wih, Whh, bih, bhh, gatesws);
    kLstm<<<128, 256, 0, stream>>>(gatesws, c0, out + OFF_H1, out + OFF_C1);
    // seq-energy GEMM (+fused scatter) before kLogits so the W_lo overlay is legal
    kSeqGemm<<<256, 512, 0, stream>>>(seqs, wskh, wskl, out + OFF_H1,
                                      mask, extix, flag, copyenc);
    kQ<<<128, 256, 0, stream>>>(out + OFF_H1, Wkey, bkey, qws, kbws);
    kEnergies<<<256, 256, 0, stream>>>(enc, qws, kbws, enws);
    kSoftmax<<<64, 256, 0, stream>>>(enws, out + OFF_ATTN);
    kContext<<<512, 256, 0, stream>>>(enc, out + OFF_ATTN, out + OFF_CTX);
    kCombined<<<128, 256, 0, stream>>>(out + OFF_H1, out + OFF_CTX, Wcomb, bcomb, combws);
    kLogits<<<500, 256, 0, stream>>>(combws, Wout, bout, logitsws);
    kFinal1<<<1024, 256, 0, stream>>>(logitsws, copyenc, out + OFF_OUT0, rmax);
    kFinal2<<<1024, 256, 0, stream>>>(out + OFF_OUT0, rmax, rsum);
    kFinal3<<<1024, 256, 0, stream>>>(out + OFF_OUT0, rmax, rsum);
}

// Round 6
// 572.947 us; speedup vs baseline: 1.0430x; 1.0326x over previous
//
#include <hip/hip_runtime.h>
#include <math.h>

#define B_N    64
#define H_N    512
#define V_N    32000
#define S_N    512
#define VEXT   32050
#define INF_F  1000000000000.0f

typedef __attribute__((ext_vector_type(4))) float floatx4;
typedef __attribute__((ext_vector_type(8))) __bf16 bf16x8;

// ---- output layout (floats) ----
#define OFF_OUT0 0
#define OFF_CTX  (B_N * VEXT)                 // 2051200
#define OFF_H1   (OFF_CTX + B_N * H_N)        // 2083968
#define OFF_C1   (OFF_H1 + B_N * H_N)        // 2116736
#define OFF_ATTN (OFF_C1 + B_N * H_N)        // 2149504

// ---- workspace layout (32-bit words) ----
#define WS_FLAG   0
#define WS_X      16
#define WS_GATES  (WS_X + B_N * H_N)                  // 32784
#define WS_Q      (WS_GATES + B_N * 4 * H_N)          // 163856
#define WS_KB     (WS_Q + B_N * H_N)                  // 196624
#define WS_EN     (WS_KB + B_N)                       // 196688
#define WS_COMB   (WS_EN + B_N * S_N)                 // 229456
#define WS_SEQE   (WS_COMB + B_N * H_N)               // 262224 (unused; kept for layout)
#define WS_WSKBF  (WS_SEQE + B_N * S_N)               // 294992 (512*512 ushort, swizzled, HI part)
#define WS_LOGITS (WS_WSKBF + (H_N * H_N) / 2)        // 426064
// W_lo (512*512 ushort = 131072 words) OVERLAYS the head of WS_LOGITS.
// Legal because kSeqGemm (reader) completes before kLogits (writer) on the stream.
#define WS_COPY   (WS_LOGITS + B_N * V_N)             // 2474064
#define WS_RMAX   (WS_COPY + B_N * VEXT)              // 4525264 (64 uints)
#define WS_RSUM   (WS_RMAX + B_N)                     // +64 floats

__device__ __forceinline__ float sigm(float x) { return 1.0f / (1.0f + expf(-x)); }

__device__ __forceinline__ unsigned short f2bf(float f) {
    unsigned u = __float_as_uint(f);
    u += 0x7fffu + ((u >> 16) & 1u);   // round-to-nearest-even
    return (unsigned short)(u >> 16);
}
__device__ __forceinline__ float bf2f(unsigned short h) {
    return __uint_as_float(((unsigned)h) << 16);
}

// order-preserving float<->uint encode for atomicMax-based scatter-max
__device__ __forceinline__ unsigned enc_f(float f) {
    unsigned u = __float_as_uint(f);
    return (u & 0x80000000u) ? ~u : (u | 0x80000000u);
}
__device__ __forceinline__ float dec_f(unsigned e) {
    unsigned u = (e & 0x80000000u) ? (e & 0x7fffffffu) : ~e;
    return __uint_as_float(u);
}

// ---------- fused prologue: detect mask width | convert W hi/lo | fill copy | zero ctx ----
// blocks [0]           : mask storage-width detect -> flag
// blocks [1, 129)      : W_seqkey f32 -> bf16 hi/lo, pre-swizzled B-fragment order
// blocks [129, 2133)   : copyenc = enc(-INF); first block also inits rmax/rsum
// blocks [2133, 2165)  : ctx = 0
__global__ __launch_bounds__(256) void kPre(
        const unsigned int* __restrict__ m, int* __restrict__ flag,
        const float* __restrict__ W, unsigned short* __restrict__ swzh,
        unsigned short* __restrict__ swzl, unsigned int* __restrict__ copyenc,
        unsigned int* __restrict__ rmax, float* __restrict__ rsum,
        float* __restrict__ ctx) {
    const int bx = blockIdx.x, tid = threadIdx.x;
    if (bx == 0) {
        __shared__ int any;
        if (tid == 0) any = 0;
        __syncthreads();
        int loc = 0;
        for (int i = tid; i < 8192; i += 256) loc |= (m[i] > 1u) ? 1 : 0;
        if (loc) any = 1;
        __syncthreads();
        if (tid == 0) *flag = any;   // 1 => byte storage, 0 => int32 storage
    } else if (bx < 129) {
        // layout: swz[((t*16+kc)*64+lane)*8 + j] = W[(t*16+(lane&15))*512 + kc*32 + (lane>>4)*8 + j]
        const int g = (bx - 1) * 256 + tid;            // 32768 threads, 8 elems each
        const int t = g >> 10, kc = (g >> 6) & 15, lane = g & 63;
        const int r = t * 16 + (lane & 15);
        const int k = kc * 32 + (lane >> 4) * 8;
        const float* src = W + (size_t)r * 512 + k;
        ushort4 h0, h1, l0, l1;
        const float4 v0 = *(const float4*)(src);
        const float4 v1 = *(const float4*)(src + 4);
        h0.x = f2bf(v0.x); l0.x = f2bf(v0.x - bf2f(h0.x));
        h0.y = f2bf(v0.y); l0.y = f2bf(v0.y - bf2f(h0.y));
        h0.z = f2bf(v0.z); l0.z = f2bf(v0.z - bf2f(h0.z));
        h0.w = f2bf(v0.w); l0.w = f2bf(v0.w - bf2f(h0.w));
        h1.x = f2bf(v1.x); l1.x = f2bf(v1.x - bf2f(h1.x));
        h1.y = f2bf(v1.y); l1.y = f2bf(v1.y - bf2f(h1.y));
        h1.z = f2bf(v1.z); l1.z = f2bf(v1.z - bf2f(h1.z));
        h1.w = f2bf(v1.w); l1.w = f2bf(v1.w - bf2f(h1.w));
        *(ushort4*)(swzh + (size_t)g * 8) = h0;
        *(ushort4*)(swzh + (size_t)g * 8 + 4) = h1;
        *(ushort4*)(swzl + (size_t)g * 8) = l0;
        *(ushort4*)(swzl + (size_t)g * 8 + 4) = l1;
    } else if (bx < 2133) {
        const int fb = bx - 129;
        const unsigned NE = enc_f(-INF_F);
        if (fb == 0 && tid < B_N) {
            rmax[tid] = 0u;
            rsum[tid] = 0.0f;
        }
        int i0 = (fb * 256 + tid) * 4;
#pragma unroll
        for (int k = 0; k < 4; k++) {
            int i = i0 + k;
            if (i < B_N * VEXT) copyenc[i] = NE;
        }
    } else {
        const int zb = bx - 2133;                      // 32 blocks zero 32768 floats
        const float4 z4 = {0.f, 0.f, 0.f, 0.f};
        *(float4*)(ctx + (size_t)(zb * 256 + tid) * 4) = z4;
    }
}

// ---------- x = [embed[id] | prev_context] @ W_reduce.T + b_reduce ----------
__global__ __launch_bounds__(256) void kEmbedReduce(
        const int* __restrict__ ids, const float* __restrict__ embed,
        const float* __restrict__ pctx, const float* __restrict__ Wred,
        const float* __restrict__ bred, float* __restrict__ x) {
    __shared__ float xc[1024];
    const int tid = threadIdx.x;
    const int b = blockIdx.x >> 1, half = blockIdx.x & 1;
    const float* er = embed + (size_t)ids[b] * 512;
    xc[tid] = er[tid];               xc[tid + 256] = er[tid + 256];
    xc[512 + tid] = pctx[b * 512 + tid]; xc[512 + tid + 256] = pctx[b * 512 + tid + 256];
    __syncthreads();
    const int j = half * 256 + tid;
    const float4* w4 = (const float4*)(Wred + (size_t)j * 1024);
    const float4* x4 = (const float4*)xc;
    float acc = bred[j];
    for (int k = 0; k < 256; k++) {
        float4 w = w4[k], xv = x4[k];
        acc += w.x * xv.x + w.y * xv.y + w.z * xv.z + w.w * xv.w;
    }
    x[b * 512 + j] = acc;
}

// ---------- gates = x @ W_ih.T + h0 @ W_hh.T + b_ih + b_hh ----------
__global__ __launch_bounds__(256) void kGates(
        const float* __restrict__ x, const float* __restrict__ h0,
        const float* __restrict__ Wih, const float* __restrict__ Whh,
        const float* __restrict__ bih, const float* __restrict__ bhh,
        float* __restrict__ gates) {
    __shared__ float xl[512], hl[512];
    const int tid = threadIdx.x;
    const int b = blockIdx.x >> 3, part = blockIdx.x & 7;
    xl[tid] = x[b * 512 + tid];  xl[tid + 256] = x[b * 512 + tid + 256];
    hl[tid] = h0[b * 512 + tid]; hl[tid + 256] = h0[b * 512 + tid + 256];
    __syncthreads();
    const int j = part * 256 + tid;
    const float4* wi4 = (const float4*)(Wih + (size_t)j * 512);
    const float4* wh4 = (const float4*)(Whh + (size_t)j * 512);
    const float4* x4 = (const float4*)xl;
    const float4* h4 = (const float4*)hl;
    float acc = bih[j] + bhh[j];
    for (int k = 0; k < 128; k++) {
        float4 w = wi4[k], xv = x4[k];
        acc += w.x * xv.x + w.y * xv.y + w.z * xv.z + w.w * xv.w;
    }
    for (int k = 0; k < 128; k++) {
        float4 w = wh4[k], hv = h4[k];
        acc += w.x * hv.x + w.y * hv.y + w.z * hv.z + w.w * hv.w;
    }
    gates[(size_t)b * 2048 + j] = acc;
}

// ---------- LSTM elementwise (PyTorch i,f,g,o order) ----------
__global__ __launch_bounds__(256) void kLstm(
        const float* __restrict__ gates, const float* __restrict__ c0,
        float* __restrict__ h1o, float* __restrict__ c1o) {
    const int idx = blockIdx.x * 256 + threadIdx.x;  // < 32768
    const int b = idx >> 9, j = idx & 511;
    const float gi = gates[(size_t)b * 2048 + j];
    const float gf = gates[(size_t)b * 2048 + 512 + j];
    const float gg = gates[(size_t)b * 2048 + 1024 + j];
    const float go = gates[(size_t)b * 2048 + 1536 + j];
    const float cp = c0[idx];
    const float c1 = sigm(gf) * cp + sigm(gi) * tanhf(gg);
    const float h1 = sigm(go) * tanhf(c1);
    h1o[idx] = h1;
    c1o[idx] = c1;
}

// ---------- q[b,k] = sum_h h1[b,h]*W_key[h,k]; kb[b] = b_key . h1[b] ----------
__global__ __launch_bounds__(256) void kQ(
        const float* __restrict__ h1, const float* __restrict__ Wkey,
        const float* __restrict__ bkey, float* __restrict__ q, float* __restrict__ kb) {
    __shared__ float hl[512];
    __shared__ float rd[256];
    const int tid = threadIdx.x;
    const int b = blockIdx.x >> 1, half = blockIdx.x & 1;
    hl[tid] = h1[b * 512 + tid]; hl[tid + 256] = h1[b * 512 + tid + 256];
    __syncthreads();
    const int k = half * 256 + tid;
    float acc = 0.f;
#pragma unroll 4
    for (int h = 0; h < 512; h++) acc += hl[h] * Wkey[(size_t)h * 512 + k];
    q[b * 512 + k] = acc;
    if (half == 0) {   // block-uniform branch
        float p = bkey[tid] * hl[tid] + bkey[tid + 256] * hl[tid + 256];
        rd[tid] = p; __syncthreads();
        for (int st = 128; st > 0; st >>= 1) {
            if (tid < st) rd[tid] += rd[tid + st];
            __syncthreads();
        }
        if (tid == 0) kb[b] = rd[0];
    }
}

// ---------- energies[b,s] = enc[b,s,:].q[b] + kb[b]; mask rows summing to 0 ----------
__global__ __launch_bounds__(256) void kEnergies(
        const float* __restrict__ enc, const float* __restrict__ q,
        const float* __restrict__ kb, float* __restrict__ energ) {
    __shared__ float ql[512];
    __shared__ float pe[256], ps[256];
    const int tid = threadIdx.x;
    const int b = blockIdx.x >> 2;
    const int sc = (blockIdx.x & 3) * 128;
    ql[tid] = q[b * 512 + tid]; ql[tid + 256] = q[b * 512 + tid + 256];
    __syncthreads();
    const int r = tid & 127, hi = tid >> 7;
    const float4* row4 = (const float4*)(enc + (size_t)(b * 512 + sc + r) * 512 + hi * 256);
    const float4* q4 = (const float4*)(ql + hi * 256);
    float e = 0.f, ssum = 0.f;
#pragma unroll 4
    for (int k = 0; k < 64; k++) {
        float4 ev = row4[k], qv = q4[k];
        e += ev.x * qv.x + ev.y * qv.y + ev.z * qv.z + ev.w * qv.w;
        ssum += ev.x + ev.y + ev.z + ev.w;
    }
    pe[tid] = e; ps[tid] = ssum;
    __syncthreads();
    if (tid < 128) {
        float ee = pe[tid] + pe[tid + 128] + kb[b];
        float sm = ps[tid] + ps[tid + 128];
        if (sm == 0.0f) ee = 1e-12f;        // enc_mask semantics
        energ[b * 512 + sc + tid] = ee;
    }
}

// ---------- softmax over S per b ----------
__global__ __launch_bounds__(256) void kSoftmax(
        const float* __restrict__ energ, float* __restrict__ attn) {
    __shared__ float el[512];
    __shared__ float rd[256];
    const int tid = threadIdx.x, b = blockIdx.x;
    el[tid] = energ[b * 512 + tid]; el[tid + 256] = energ[b * 512 + tid + 256];
    __syncthreads();
    rd[tid] = fmaxf(el[tid], el[tid + 256]); __syncthreads();
    for (int st = 128; st > 0; st >>= 1) {
        if (tid < st) rd[tid] = fmaxf(rd[tid], rd[tid + st]);
        __syncthreads();
    }
    const float m = rd[0]; __syncthreads();
    float v0 = expf(el[tid] - m), v1 = expf(el[tid + 256] - m);
    rd[tid] = v0 + v1; __syncthreads();
    for (int st = 128; st > 0; st >>= 1) {
        if (tid < st) rd[tid] += rd[tid + st];
        __syncthreads();
    }
    const float inv = 1.0f / rd[0];
    attn[b * 512 + tid] = v0 * inv;
    attn[b * 512 + tid + 256] = v1 * inv;
}

// ---------- context[b,h] = sum_s attn[b,s]*enc[b,s,h]  (atomicAdd partials) ----------
__global__ __launch_bounds__(256) void kContext(
        const float* __restrict__ enc, const float* __restrict__ attn,
        float* __restrict__ ctx) {
    __shared__ float al[64];
    const int tid = threadIdx.x;
    const int b = blockIdx.x >> 3, sc = (blockIdx.x & 7) * 64;
    if (tid < 64) al[tid] = attn[b * 512 + sc + tid];
    __syncthreads();
    float a0 = 0.f, a1 = 0.f;
    for (int s = 0; s < 64; s++) {
        const float* row = enc + (size_t)(b * 512 + sc + s) * 512;
        const float av = al[s];
        a0 += av * row[tid];
        a1 += av * row[tid + 256];
    }
    atomicAdd(&ctx[b * 512 + tid], a0);
    atomicAdd(&ctx[b * 512 + tid + 256], a1);
}

// ---------- combined = tanh([h1|ctx] @ W_comb.T + b_comb) ----------
__global__ __launch_bounds__(256) void kCombined(
        const float* __restrict__ h1, const float* __restrict__ ctx,
        const float* __restrict__ Wcomb, const float* __restrict__ bcomb,
        float* __restrict__ comb) {
    __shared__ float hc[1024];
    const int tid = threadIdx.x;
    const int b = blockIdx.x >> 1, half = blockIdx.x & 1;
    hc[tid] = h1[b * 512 + tid];        hc[tid + 256] = h1[b * 512 + tid + 256];
    hc[512 + tid] = ctx[b * 512 + tid]; hc[512 + tid + 256] = ctx[b * 512 + tid + 256];
    __syncthreads();
    const int j = half * 256 + tid;
    const float4* w4 = (const float4*)(Wcomb + (size_t)j * 1024);
    const float4* x4 = (const float4*)hc;
    float acc = bcomb[j];
    for (int k = 0; k < 256; k++) {
        float4 w = w4[k], xv = x4[k];
        acc += w.x * xv.x + w.y * xv.y + w.z * xv.z + w.w * xv.w;
    }
    comb[b * 512 + j] = tanhf(acc);
}

// ---------- logits[b,v] = combined[b] . W_out[v] + b_out[v]  (f32, k-split x4) ----------
__global__ __launch_bounds__(256) void kLogits(
        const float* __restrict__ comb, const float* __restrict__ Wout,
        const float* __restrict__ bout, float* __restrict__ logits) {
    __shared__ float cl[4][32][64];   // [kq][kk][b] also reused as reduction scratch
    const int tid = threadIdx.x;
    const int vt = tid & 63, kq = tid >> 6;
    const int v = blockIdx.x * 64 + vt;
    float acc[64];
#pragma unroll
    for (int i = 0; i < 64; i++) acc[i] = 0.f;
    for (int kc = 0; kc < 4; kc++) {
        __syncthreads();
        {
            const float4* s4 = (const float4*)(comb + (size_t)vt * 512 + kq * 128 + kc * 32);
#pragma unroll
            for (int qq = 0; qq < 8; qq++) {
                float4 vv = s4[qq];
                cl[kq][qq * 4 + 0][vt] = vv.x; cl[kq][qq * 4 + 1][vt] = vv.y;
                cl[kq][qq * 4 + 2][vt] = vv.z; cl[kq][qq * 4 + 3][vt] = vv.w;
            }
        }
        __syncthreads();
        float wreg[32];
        const float4* w4 = (const float4*)(Wout + (size_t)v * 512 + kq * 128 + kc * 32);
#pragma unroll
        for (int qq = 0; qq < 8; qq++) {
            float4 wv = w4[qq];
            wreg[qq * 4 + 0] = wv.x; wreg[qq * 4 + 1] = wv.y;
            wreg[qq * 4 + 2] = wv.z; wreg[qq * 4 + 3] = wv.w;
        }
#pragma unroll
        for (int kk = 0; kk < 32; kk++) {
            const float wv = wreg[kk];
            const float4* cp = (const float4*)&cl[kq][kk][0];
#pragma unroll
            for (int b4 = 0; b4 < 16; b4++) {
                float4 c4 = cp[b4];
                acc[b4 * 4 + 0] += wv * c4.x; acc[b4 * 4 + 1] += wv * c4.y;
                acc[b4 * 4 + 2] += wv * c4.z; acc[b4 * 4 + 3] += wv * c4.w;
            }
        }
    }
    float* red = &cl[0][0][0];
    __syncthreads();
    if (kq >= 2) {
#pragma unroll
        for (int b = 0; b < 64; b++) red[(kq - 2) * 4096 + vt * 64 + b] = acc[b];
    }
    __syncthreads();
    if (kq < 2) {
#pragma unroll
        for (int b = 0; b < 64; b++) acc[b] += red[kq * 4096 + vt * 64 + b];
    }
    __syncthreads();
    if (kq == 1) {
#pragma unroll
        for (int b = 0; b < 64; b++) red[vt * 64 + b] = acc[b];
    }
    __syncthreads();
    if (kq == 0) {
        const float bo = bout[v];
#pragma unroll
        for (int b = 0; b < 64; b++)
            logits[(size_t)b * 32000 + v] = acc[b] + red[vt * 64 + b] + bo;
    }
}

// ---------- seq-energy GEMM + fused scatter-max ----------
// seq_e[m] = sum_h tanh( (seqs @ W_seqkey.T)[m,h] ) * h1[b,h], then atomicMax into copyenc.
// bf16 MFMA hi/lo split: K = Ah*Bh + Al*Bh + Ah*Bl (~f32 precision).
// v5: MT=64 -> 512 blocks, 2 blocks/CU co-resident (r2-vs-r3 evidence: 2/CU at 4x
// traffic beat 1/CU -> overlap is the lever, not L2 traffic). LDS 39KB, acc[4][4],
// VGPR ~100 <= 128 tier. Per-output FP order identical to the verified r3/r5 body.
#define ACH 136   // chunk LDS row stride in ushorts: 128 + 8 pad
__global__ __launch_bounds__(512, 2) void kSeqGemm(
        const float* __restrict__ seqs, const unsigned short* __restrict__ swzh,
        const unsigned short* __restrict__ swzl, const float* __restrict__ h1g,
        const void* __restrict__ mask, const int* __restrict__ extix,
        const int* __restrict__ flag, unsigned int* __restrict__ copyenc) {
    __shared__ unsigned short a_hi[64 * ACH];   // 17408 B
    __shared__ unsigned short a_lo[64 * ACH];   // 17408 B
    __shared__ float h1l[512];
    __shared__ float partf[8][64];
    const int tid = threadIdx.x;
    const int m0 = blockIdx.x * 64;
    const int b = blockIdx.x >> 3;           // 8 blocks per batch row
    const int w = tid >> 6;
    const int lane = tid & 63;
    const int quad = lane >> 4;
    const int c16 = lane & 15;

    h1l[tid] = h1g[b * 512 + tid];

    floatx4 acc[4][4];
    const floatx4 zf = {0.f, 0.f, 0.f, 0.f};
#pragma unroll
    for (int i = 0; i < 4; i++)
#pragma unroll
        for (int j = 0; j < 4; j++) acc[i][j] = zf;

    const size_t boff = (size_t)(w * 64) * 512 + (size_t)lane * 8;
    const unsigned short* bh = swzh + boff;
    const unsigned short* bl = swzl + boff;

    // staging geometry: 8 threads/row, 16 floats each per chunk
    const int srow = tid >> 3, sq = tid & 7;

    for (int c = 0; c < 4; c++) {
        __syncthreads();   // previous chunk's readers done
        {
            const float* src = seqs + (size_t)(m0 + srow) * 512 + c * 128 + sq * 16;
            unsigned short* dh = &a_hi[srow * ACH + sq * 16];
            unsigned short* dl = &a_lo[srow * ACH + sq * 16];
#pragma unroll
            for (int i = 0; i < 4; i++) {
                float4 v = *(const float4*)(src + i * 4);
                ushort4 hv, lv;
                hv.x = f2bf(v.x); lv.x = f2bf(v.x - bf2f(hv.x));
                hv.y = f2bf(v.y); lv.y = f2bf(v.y - bf2f(hv.y));
                hv.z = f2bf(v.z); lv.z = f2bf(v.z - bf2f(hv.z));
                hv.w = f2bf(v.w); lv.w = f2bf(v.w - bf2f(hv.w));
                *(ushort4*)(dh + i * 4) = hv;
                *(ushort4*)(dl + i * 4) = lv;
            }
        }
        __syncthreads();
#pragma unroll
        for (int kcl = 0; kcl < 4; kcl++) {
            const int kc = c * 4 + kcl;
            bf16x8 bhf[4], blf[4];
#pragma unroll
            for (int nt = 0; nt < 4; nt++) {
                bhf[nt] = *(const bf16x8*)(bh + (size_t)(nt * 16 + kc) * 512);
                blf[nt] = *(const bf16x8*)(bl + (size_t)(nt * 16 + kc) * 512);
            }
#pragma unroll
            for (int ms = 0; ms < 4; ms++) {
                bf16x8 ah = *(const bf16x8*)&a_hi[(ms * 16 + c16) * ACH + kcl * 32 + quad * 8];
                bf16x8 al = *(const bf16x8*)&a_lo[(ms * 16 + c16) * ACH + kcl * 32 + quad * 8];
#pragma unroll
                for (int nt = 0; nt < 4; nt++) {
                    acc[ms][nt] = __builtin_amdgcn_mfma_f32_16x16x32_bf16(
                        ah, bhf[nt], acc[ms][nt], 0, 0, 0);
                    acc[ms][nt] = __builtin_amdgcn_mfma_f32_16x16x32_bf16(
                        al, bhf[nt], acc[ms][nt], 0, 0, 0);
                    acc[ms][nt] = __builtin_amdgcn_mfma_f32_16x16x32_bf16(
                        ah, blf[nt], acc[ms][nt], 0, 0, 0);
                }
            }
        }
    }

    // ---- epilogue: partial over this wave's 64 cols, reduce across waves ----
    float psum[16];
#pragma unroll
    for (int i = 0; i < 16; i++) psum[i] = 0.f;
#pragma unroll
    for (int ms = 0; ms < 4; ms++)
#pragma unroll
        for (int nt = 0; nt < 4; nt++) {
            const float hv = h1l[w * 64 + nt * 16 + c16];
#pragma unroll
            for (int r = 0; r < 4; r++)
                psum[ms * 4 + r] += tanhf(acc[ms][nt][r]) * hv;   // D: row=quad*4+r, col=c16
        }
#pragma unroll
    for (int d = 1; d < 16; d <<= 1)
#pragma unroll
        for (int i = 0; i < 16; i++) psum[i] += __shfl_xor(psum[i], d);
    if (c16 == 0) {
#pragma unroll
        for (int ms = 0; ms < 4; ms++)
#pragma unroll
            for (int r = 0; r < 4; r++)
                partf[w][ms * 16 + quad * 4 + r] = psum[ms * 4 + r];
    }
    __syncthreads();
    if (tid < 64) {
        float s = 0.f;
#pragma unroll
        for (int ww = 0; ww < 8; ww++) s += partf[ww][tid];
        // fused scatter-max
        const int m = m0 + tid;
        bool mk;
        if (*flag) mk = ((const unsigned char*)mask)[m] != 0;
        else       mk = ((const int*)mask)[m] != 0;
        if (mk) s = 1e-12f;
        const int idx = extix[m];
        atomicMax(&copyenc[(size_t)b * VEXT + idx], enc_f(s));
    }
}

// ---------- fused log_softmax: one block per batch row, row in registers ----------
// Replaces kFinal1/2/3 (3 launches + out0 re-read x2). Max is exact (order-free);
// exp-sum order differs from the old atomicAdd chunk order, but that order was
// already nondeterministic run-to-run -- this makes lse deterministic.
__global__ __launch_bounds__(1024) void kFinal(
        const float* __restrict__ logits, const unsigned int* __restrict__ copyenc,
        float* __restrict__ out0) {
    __shared__ float redm[16];
    __shared__ float reds[16];
    const int b = blockIdx.x, tid = threadIdx.x;
    const float* lrow = logits + (size_t)b * 32000;
    const unsigned int* crow = copyenc + (size_t)b * VEXT;
    float* orow = out0 + (size_t)b * VEXT;
    float o[32];
    float lm = -3.0e38f;
#pragma unroll
    for (int k = 0; k < 32; k++) {
        const int j = k * 1024 + tid;
        if (j < VEXT) {
            float ext = (j < 32000) ? lrow[j] : 0.0f;
            float cv = dec_f(crow[j]);
            if (cv == -INF_F) cv = 0.0f;
            float v = ext + cv;
            if (v == 0.0f) v = -INF_F;
            o[k] = v;
            lm = fmaxf(lm, v);
        } else {
            o[k] = -INF_F;
        }
    }
#pragma unroll
    for (int d = 1; d < 64; d <<= 1) lm = fmaxf(lm, __shfl_xor(lm, d));
    if ((tid & 63) == 0) redm[tid >> 6] = lm;
    __syncthreads();
    float m = redm[0];
#pragma unroll
    for (int i = 1; i < 16; i++) m = fmaxf(m, redm[i]);
    float s = 0.f;
#pragma unroll
    for (int k = 0; k < 32; k++) s += expf(o[k] - m);
#pragma unroll
    for (int d = 1; d < 64; d <<= 1) s += __shfl_xor(s, d);
    if ((tid & 63) == 0) reds[tid >> 6] = s;
    __syncthreads();
    float tot = reds[0];
#pragma unroll
    for (int i = 1; i < 16; i++) tot += reds[i];
    const float lse = m + logf(tot);
#pragma unroll
    for (int k = 0; k < 32; k++) {
        const int j = k * 1024 + tid;
        if (j < VEXT) orow[j] = o[k] - lse;
    }
}

extern "C" void kernel_launch(void* const* d_in, const int* in_sizes, int n_in,
                              void* d_out, int out_size, void* d_ws, size_t ws_size,
                              hipStream_t stream) {
    const int*   ids   = (const int*)d_in[0];
    const float* pctx  = (const float*)d_in[1];
    const float* h0    = (const float*)d_in[2];
    const float* c0    = (const float*)d_in[3];
    const float* enc   = (const float*)d_in[4];
    const float* seqs  = (const float*)d_in[5];
    const void*  mask  = d_in[6];
    const int*   extix = (const int*)d_in[7];
    const float* embed = (const float*)d_in[8];
    const float* Wred  = (const float*)d_in[9];
    const float* bred  = (const float*)d_in[10];
    const float* Wkey  = (const float*)d_in[11];
    const float* bkey  = (const float*)d_in[12];
    const float* Wcomb = (const float*)d_in[13];
    const float* bcomb = (const float*)d_in[14];
    const float* Wseqk = (const float*)d_in[15];
    const float* Wih   = (const float*)d_in[16];
    const float* Whh   = (const float*)d_in[17];
    const float* bih   = (const float*)d_in[18];
    const float* bhh   = (const float*)d_in[19];
    const float* Wout  = (const float*)d_in[20];
    const float* bout  = (const float*)d_in[21];
    (void)in_sizes; (void)n_in; (void)out_size; (void)ws_size;

    float* out = (float*)d_out;
    float* ws = (float*)d_ws;
    int* flag = (int*)ws;
    float* xws = ws + WS_X;
    float* gatesws = ws + WS_GATES;
    float* qws = ws + WS_Q;
    float* kbws = ws + WS_KB;
    float* enws = ws + WS_EN;
    float* combws = ws + WS_COMB;
    unsigned short* wskh = (unsigned short*)(ws + WS_WSKBF);
    float* logitsws = ws + WS_LOGITS;
    unsigned short* wskl = (unsigned short*)(ws + WS_LOGITS);  // overlay; dead before kLogits
    unsigned int* copyenc = (unsigned int*)(ws + WS_COPY);
    unsigned int* rmax = (unsigned int*)(ws + WS_RMAX);
    float* rsum = ws + WS_RSUM;

    // fused prologue (detect + convertW + fillCopy + ctx zero)
    kPre<<<2165, 256, 0, stream>>>((const unsigned int*)mask, flag, Wseqk, wskh, wskl,
                                   copyenc, rmax, rsum, out + OFF_CTX);
    kEmbedReduce<<<128, 256, 0, stream>>>(ids, embed, pctx, Wred, bred, xws);
    kGates<<<512, 256, 0, stream>>>(xws, h0, Wih, Whh, bih, bhh, gatesws);
    kLstm<<<128, 256, 0, stream>>>(gatesws, c0, out + OFF_H1, out + OFF_C1);
    // seq-energy GEMM (+fused scatter) before kLogits so the W_lo overlay is legal
    kSeqGemm<<<512, 512, 0, stream>>>(seqs, wskh, wskl, out + OFF_H1,
                                      mask, extix, flag, copyenc);
    kQ<<<128, 256, 0, stream>>>(out + OFF_H1, Wkey, bkey, qws, kbws);
    kEnergies<<<256, 256, 0, stream>>>(enc, qws, kbws, enws);
    kSoftmax<<<64, 256, 0, stream>>>(enws, out + OFF_ATTN);
    kContext<<<512, 256, 0, stream>>>(enc, out + OFF_ATTN, out + OFF_CTX);
    kCombined<<<128, 256, 0, stream>>>(out + OFF_H1, out + OFF_CTX, Wcomb, bcomb, combws);
    kLogits<<<500, 256, 0, stream>>>(combws, Wout, bout, logitsws);
    kFinal<<<64, 1024, 0, stream>>>(logitsws, copyenc, out + OFF_OUT0);
}